// Round 10
// baseline (80.105 us; speedup 1.0000x reference)
//
#include <hip/hip_runtime.h>
#include <math.h>

// Problem constants: B=64, F=240, J=22, 16 segments, 5 paths.
#define BB 64
#define FF 240
#define NJ 22
#define NFRM (BB * FF)
#define FPW 3          // frames per wave
#define FPB 12         // frames per 256-thread block (4 waves)

// Segment joint tables bit-packed 5 bits/entry into constexpr immediates.
#define PK8(a0,a1,a2,a3,a4,a5,a6,a7) \
  (  (unsigned long long)(a0)        | ((unsigned long long)(a1) << 5)  \
   | ((unsigned long long)(a2) << 10)| ((unsigned long long)(a3) << 15) \
   | ((unsigned long long)(a4) << 20)| ((unsigned long long)(a5) << 25) \
   | ((unsigned long long)(a6) << 30)| ((unsigned long long)(a7) << 35) )
static constexpr unsigned long long SEG_S_LO = PK8(2,5,8,1,4,7,3,6);
static constexpr unsigned long long SEG_S_HI = PK8(9,12,14,17,19,13,16,18);
static constexpr unsigned long long SEG_E_LO = PK8(5,8,11,4,7,10,6,9);
static constexpr unsigned long long SEG_E_HI = PK8(12,15,17,19,21,16,18,20);
// Path offset/count tables, 5 bits/entry.
static constexpr unsigned PO_PK = 0u | (3u<<5) | (6u<<10) | (10u<<15) | (13u<<20);
static constexpr unsigned PC_PK = 3u | (3u<<5) | (4u<<10) | (3u<<15)  | (3u<<20);

struct F3 { float x, y, z; };
__device__ __forceinline__ F3 sub(F3 a, F3 b){ return {a.x-b.x, a.y-b.y, a.z-b.z}; }
__device__ __forceinline__ F3 crs(F3 a, F3 b){
    return {fmaf(a.y, b.z, -a.z*b.y), fmaf(a.z, b.x, -a.x*b.z), fmaf(a.x, b.y, -a.y*b.x)};
}
__device__ __forceinline__ float dt(F3 a, F3 b){ return fmaf(a.x, b.x, fmaf(a.y, b.y, a.z*b.z)); }
__device__ __forceinline__ float clamp1(float d){ return fminf(fmaxf(d, -1.0f), 1.0f); }

// Branchless asin, Abramowitz-Stegun 4.4.45 (3-term), |err| <= 6.8e-5 abs.
// __builtin_amdgcn_sqrtf = raw v_sqrt_f32 (no libm range-fixup sequence).
__device__ __forceinline__ float asin_fast(float d){
    float ax = fabsf(d);
    float p = fmaf(fmaf(fmaf(-0.0187293f, ax, 0.0742610f), ax, -0.2121144f), ax, 1.5707288f);
    float r = 1.57079632679f - __builtin_amdgcn_sqrtf(1.0f - ax) * p;
    return copysignf(r, d);
}
// Raw v_rsq_f32 (libm rsqrtf may emit an accuracy fixup without fast-math).
__device__ __forceinline__ float rsq_fast(float x){ return __builtin_amdgcn_rsqf(x); }

// 256-thread block = 4 waves; each wave owns THREE frames (block = 12 frames).
// Each lane runs 12 independent GLI pair-chains (3 frames x 4 pairs),
// phase-parallel; __launch_bounds__(256,3) (~170 VGPR cap) gives the allocator
// room to keep all chains live instead of re-serializing them.
__global__ void __launch_bounds__(256, 3) k_main(const float* __restrict__ m1,
                                                 const float* __restrict__ m2,
                                                 float* __restrict__ gp,
                                                 int* __restrict__ flags){
    __shared__ __align__(8)  float pts[4][2][FPW*66];     // [wave][motion][frame*66+idx]
    __shared__ __align__(8)  float seg[4][FPW][2][16][6]; // [wave][frame][motion][seg][6]
    __shared__ float g[4][FPW][256];                      // [wave][frame][m*16+n]
    __shared__ float ext[4][FPW][8];                      // [wave][frame][{nx,xx,nz,xz} x 2 mot]
    int tid = threadIdx.x;
    int w = tid >> 6, lane = tid & 63;
    int fr0 = blockIdx.x * FPB + w * FPW;   // this wave's frames: fr0 .. fr0+2

    // Stage FPW frames x 66 floats per motion = 99 float2 per motion (contiguous).
    const float2* gs1 = (const float2*)(m1 + (size_t)fr0 * 66);
    const float2* gs2 = (const float2*)(m2 + (size_t)fr0 * 66);
    for (int u = lane; u < 2*33*FPW; u += 64){
        bool a = u < 33*FPW;
        int v = a ? u : u - 33*FPW;
        ((float2*)pts[w][a ? 0 : 1])[v] = (a ? gs1 : gs2)[v];
    }
    __syncthreads();

    // Segment-endpoint table: FPW x 2 x 16 = 96 entries over 64 lanes.
    for (int u = lane; u < 32*FPW; u += 64){
        int m = u & 15, mot = (u >> 4) & 1, f = u >> 5;
        unsigned long long ps = (m < 8) ? SEG_S_LO : SEG_S_HI;
        unsigned long long pe = (m < 8) ? SEG_E_LO : SEG_E_HI;
        int sh = (m & 7) * 5;
        int js = (int)((ps >> sh) & 31);
        int je = (int)((pe >> sh) & 31);
        const float* P = &pts[w][mot][f * 66];
        float* d = &seg[w][f][mot][m][0];
        d[0] = P[js*3]; d[1] = P[js*3+1]; d[2] = P[js*3+2];
        d[3] = P[je*3]; d[4] = P[je*3+1]; d[5] = P[je*3+2];
    }
    // Bbox extrema: FPW x 2 motions x {x,z} x {min,max} = 24 lanes, one each.
    if (lane < 8*FPW){
        int f = lane >> 3;
        int sel = lane & 7;          // mot = sel>>2; 0=nx 1=xx 2=nz 3=xz
        int mot = sel >> 2;
        int c = sel & 2;             // 0 -> x, 2 -> z
        bool mx = sel & 1;           // max via -min(-v)
        const float* P = &pts[w][mot][f * 66];
        float a = 1e30f;
        #pragma unroll
        for (int j = 0; j < NJ; ++j){
            float v = P[j*3 + c];
            a = fminf(a, mx ? -v : v);
        }
        ext[w][f][sel] = mx ? -a : a;
    }
    __syncthreads();

    // GLI: 12 independent pair-chains per lane (f in 0..2, k in 0..3).
    int n = lane & 15, q = lane >> 4;

    float rd01[FPW][4], rd12[FPW][4], rd23[FPW][4], rd30[FPW][4];
    float q01[FPW][4], q12[FPW][4], q23[FPW][4], q30[FPW][4];
    float sg[FPW][4];
    #pragma unroll
    for (int f = 0; f < FPW; ++f){
        const float* B = &seg[w][f][1][n][0];
        float2 b0 = *(const float2*)(B+0);
        float2 b1 = *(const float2*)(B+2);
        float2 b2 = *(const float2*)(B+4);
        F3 s2 = {b0.x, b0.y, b1.x};
        F3 e2 = {b1.y, b2.x, b2.y};
        #pragma unroll
        for (int k = 0; k < 4; ++k){
            int m = q + 4 * k;
            const float* A = &seg[w][f][0][m][0];
            float2 a0 = *(const float2*)(A+0);
            float2 a1 = *(const float2*)(A+2);
            float2 a2 = *(const float2*)(A+4);
            F3 s1 = {a0.x, a0.y, a1.x};
            F3 e1 = {a1.y, a2.x, a2.y};
            F3 r13 = sub(s2, s1), r14 = sub(e2, s1);
            F3 r23 = sub(s2, e1), r24 = sub(e2, e1);
            F3 f0 = crs(r13, r14);
            F3 f1 = crs(r14, r24);
            F3 f2 = crs(r24, r23);
            F3 f3 = crs(r23, r13);
            float ss0 = dt(f0,f0), ss1 = dt(f1,f1), ss2 = dt(f2,f2), ss3 = dt(f3,f3);
            rd01[f][k] = dt(f0,f1); rd12[f][k] = dt(f1,f2);
            rd23[f][k] = dt(f2,f3); rd30[f][k] = dt(f3,f0);
            q01[f][k] = ss0*ss1; q12[f][k] = ss1*ss2;
            q23[f][k] = ss2*ss3; q30[f][k] = ss3*ss0;
            // (r34 x r12) . r13 == -(f3 . r14): reuse f3, skip the 5th cross.
            sg[f][k] = dt(f3, r14);
        }
    }
    // 48 independent raw v_rsq_f32.
    float i01[FPW][4], i12[FPW][4], i23[FPW][4], i30[FPW][4];
    #pragma unroll
    for (int f = 0; f < FPW; ++f)
    #pragma unroll
    for (int k = 0; k < 4; ++k){
        i01[f][k] = rsq_fast(fmaxf(q01[f][k], 1e-30f));
        i12[f][k] = rsq_fast(fmaxf(q12[f][k], 1e-30f));
        i23[f][k] = rsq_fast(fmaxf(q23[f][k], 1e-30f));
        i30[f][k] = rsq_fast(fmaxf(q30[f][k], 1e-30f));
    }
    // 48 asin groups + combine + store.
    #pragma unroll
    for (int f = 0; f < FPW; ++f)
    #pragma unroll
    for (int k = 0; k < 4; ++k){
        float t = asin_fast(clamp1(rd01[f][k] * i01[f][k]))
                + asin_fast(clamp1(rd12[f][k] * i12[f][k]))
                + asin_fast(clamp1(rd23[f][k] * i23[f][k]))
                + asin_fast(clamp1(rd30[f][k] * i30[f][k]));
        // ref: mult = (sign<=0) ? -1 : 1, sign = -sg  =>  negate when sg >= 0.
        float r = (sg[f][k] >= 0.0f ? -t : t) * 0.07957747154594767f;  // 1/(4*pi)
        g[w][f][(k << 6) | lane] = r;   // (q+4k)*16+n == 64k+lane
    }
    __syncthreads();

    // Path-pair sums: FPW x 25 = 75 outputs + FPW flags, over 64 lanes.
    for (int u = lane; u < 25*FPW + FPW; u += 64){
        if (u < 25*FPW){
            int f = u / 25, pp = u - f * 25;
            int i = pp / 5, j = pp - i * 5;
            int poi = (int)((PO_PK >> (i*5)) & 31), pci = (int)((PC_PK >> (i*5)) & 31);
            int poj = (int)((PO_PK >> (j*5)) & 31), pcj = (int)((PC_PK >> (j*5)) & 31);
            float s = 0.0f;
            for (int a = 0; a < pci; ++a)
                for (int b = 0; b < pcj; ++b)
                    s += g[w][f][(poi + a) * 16 + (poj + b)];
            int fr = fr0 + f;
            int bb = fr / FF, ff = fr - bb * FF;
            gp[((size_t)bb * 25 + pp) * FF + ff] = s;
        } else {
            int f = u - 25*FPW;
            const float* e = ext[w][f];
            flags[fr0 + f] = (e[1] >= e[4] && e[5] >= e[0] &&
                              e[3] >= e[6] && e[7] >= e[2]) ? 1 : 0;
        }
    }
}

// Masked frame-diff, max over 25 path-pairs. gp is [b][pp][f]: lane-contiguous in f.
__global__ void __launch_bounds__(256) k_vel(const float* __restrict__ gp,
                                             const int* __restrict__ flags,
                                             float* __restrict__ out){
    int b = blockIdx.x;
    int f = threadIdx.x;
    if (f >= FF - 1) return;
    const int* fl = flags + b * FF;

    int v0 = fl[f] | fl[f + 1];
    if (f > 0) v0 |= fl[f - 1];
    float mk0 = v0 ? 1.0f : 0.0f;

    int v1 = fl[f] | fl[f + 1];
    if (f + 2 < FF) v1 |= fl[f + 2];
    float mk1 = v1 ? 1.0f : 0.0f;

    const float* gb = gp + (size_t)b * 25 * FF + f;
    float mx = 0.0f;
    #pragma unroll
    for (int p = 0; p < 25; ++p){
        float g0 = gb[p * FF];
        float g1 = gb[p * FF + 1];
        float d = fabsf(g1 * mk1 - g0 * mk0);
        mx = fmaxf(mx, d);
    }
    out[b * (FF - 1) + f] = mx;
}

extern "C" void kernel_launch(void* const* d_in, const int* in_sizes, int n_in,
                              void* d_out, int out_size, void* d_ws, size_t ws_size,
                              hipStream_t stream) {
    const float* m1 = (const float*)d_in[0];
    const float* m2 = (const float*)d_in[1];
    float* gp    = (float*)d_ws;                                   // BB*25*FF floats
    int*   flags = (int*)((char*)d_ws + (size_t)BB * 25 * FF * 4); // NFRM ints
    float* out = (float*)d_out;

    k_main<<<NFRM / FPB, 256, 0, stream>>>(m1, m2, gp, flags);
    k_vel<<<BB, 256, 0, stream>>>(gp, flags, out);
}

// Round 11
// 78.550 us; speedup vs baseline: 1.0198x; 1.0198x over previous
//
#include <hip/hip_runtime.h>
#include <math.h>

// Problem constants: B=64, F=240, J=22, 16 segments, 5 paths.
#define BB 64
#define FF 240
#define NJ 22
#define NFRM (BB * FF)

// Segment joint tables bit-packed 5 bits/entry into constexpr immediates.
#define PK8(a0,a1,a2,a3,a4,a5,a6,a7) \
  (  (unsigned long long)(a0)        | ((unsigned long long)(a1) << 5)  \
   | ((unsigned long long)(a2) << 10)| ((unsigned long long)(a3) << 15) \
   | ((unsigned long long)(a4) << 20)| ((unsigned long long)(a5) << 25) \
   | ((unsigned long long)(a6) << 30)| ((unsigned long long)(a7) << 35) )
static constexpr unsigned long long SEG_S_LO = PK8(2,5,8,1,4,7,3,6);
static constexpr unsigned long long SEG_S_HI = PK8(9,12,14,17,19,13,16,18);
static constexpr unsigned long long SEG_E_LO = PK8(5,8,11,4,7,10,6,9);
static constexpr unsigned long long SEG_E_HI = PK8(12,15,17,19,21,16,18,20);
// Path offset/count tables, 5 bits/entry.
static constexpr unsigned PO_PK = 0u | (3u<<5) | (6u<<10) | (10u<<15) | (13u<<20);
static constexpr unsigned PC_PK = 3u | (3u<<5) | (4u<<10) | (3u<<15)  | (3u<<20);

struct F3 { float x, y, z; };
__device__ __forceinline__ F3 sub(F3 a, F3 b){ return {a.x-b.x, a.y-b.y, a.z-b.z}; }
__device__ __forceinline__ F3 crs(F3 a, F3 b){
    return {fmaf(a.y, b.z, -a.z*b.y), fmaf(a.z, b.x, -a.x*b.z), fmaf(a.x, b.y, -a.y*b.x)};
}
__device__ __forceinline__ float dt(F3 a, F3 b){ return fmaf(a.x, b.x, fmaf(a.y, b.y, a.z*b.z)); }
__device__ __forceinline__ float clamp1(float d){ return fminf(fmaxf(d, -1.0f), 1.0f); }

// Branchless asin, Abramowitz-Stegun 4.4.45 (3-term), |err| <= 6.8e-5 abs.
__device__ __forceinline__ float asin_fast(float d){
    float ax = fabsf(d);
    float p = fmaf(fmaf(fmaf(-0.0187293f, ax, 0.0742610f), ax, -0.2121144f), ax, 1.5707288f);
    float r = 1.57079632679f - __builtin_amdgcn_sqrtf(1.0f - ax) * p;
    return copysignf(r, d);
}

// 256-thread block = 4 waves; each wave owns TWO frames. R9 structure, minus
// the pts-LDS staging phase: seg-table builders gather straight from global
// (same cache lines, L1-merged), removing one barrier + one LDS round-trip
// from the wave-startup critical path.
__global__ void __launch_bounds__(256, 4) k_main(const float* __restrict__ m1,
                                                 const float* __restrict__ m2,
                                                 float* __restrict__ gp,
                                                 int* __restrict__ flags){
    __shared__ __align__(8) float seg[4][2][2][16][6]; // [wave][frame][motion][seg][6]
    __shared__ float g[4][2][256];                     // [wave][frame][m*16+n]
    __shared__ float ext[4][2][8];                     // [wave][frame][{nx,xx,nz,xz} x 2 mot]
    int tid = threadIdx.x;
    int w = tid >> 6, lane = tid & 63;
    int fr0 = blockIdx.x * 8 + w * 2;   // this wave's frames: fr0, fr0+1

    // Seg-table build straight from global: 2 frames x 2 motions x 16 segs = 64
    // entries, exactly one per lane.
    {
        int m = lane & 15, mot = (lane >> 4) & 1, f = lane >> 5;
        unsigned long long ps = (m < 8) ? SEG_S_LO : SEG_S_HI;
        unsigned long long pe = (m < 8) ? SEG_E_LO : SEG_E_HI;
        int sh = (m & 7) * 5;
        int js = (int)((ps >> sh) & 31);
        int je = (int)((pe >> sh) & 31);
        const float* P = (mot ? m2 : m1) + (size_t)(fr0 + f) * 66;
        float* d = &seg[w][f][mot][m][0];
        d[0] = P[js*3]; d[1] = P[js*3+1]; d[2] = P[js*3+2];
        d[3] = P[je*3]; d[4] = P[je*3+1]; d[5] = P[je*3+2];
    }
    // Bbox extrema straight from global (lines are L1-hot from the seg gather):
    // 2 frames x 2 motions x {x,z} x {min,max} = 16 lanes, one extremum each.
    if (lane < 16){
        int f = lane >> 3;
        int sel = lane & 7;          // mot = sel>>2; 0=nx 1=xx 2=nz 3=xz
        int mot = sel >> 2;
        int c = sel & 2;             // 0 -> x, 2 -> z
        bool mx = sel & 1;           // max via -min(-v)
        const float* P = (mot ? m2 : m1) + (size_t)(fr0 + f) * 66;
        float a = 1e30f;
        #pragma unroll
        for (int j = 0; j < NJ; ++j){
            float v = P[j*3 + c];
            a = fminf(a, mx ? -v : v);
        }
        ext[w][f][sel] = mx ? -a : a;
    }
    __syncthreads();

    // GLI: 8 independent pair-chains per lane (f in {0,1}, k in {0..3}).
    int n = lane & 15, q = lane >> 4;
    F3 s2f[2], e2f[2];
    #pragma unroll
    for (int f = 0; f < 2; ++f){
        const float* B = &seg[w][f][1][n][0];
        float2 b0 = *(const float2*)(B+0);
        float2 b1 = *(const float2*)(B+2);
        float2 b2 = *(const float2*)(B+4);
        s2f[f] = {b0.x, b0.y, b1.x};
        e2f[f] = {b1.y, b2.x, b2.y};
    }

    float rd01[2][4], rd12[2][4], rd23[2][4], rd30[2][4];
    float q01[2][4], q12[2][4], q23[2][4], q30[2][4];
    float sg[2][4];
    #pragma unroll
    for (int f = 0; f < 2; ++f){
        F3 s2 = s2f[f], e2 = e2f[f];
        #pragma unroll
        for (int k = 0; k < 4; ++k){
            int m = q + 4 * k;
            const float* A = &seg[w][f][0][m][0];
            float2 a0 = *(const float2*)(A+0);
            float2 a1 = *(const float2*)(A+2);
            float2 a2 = *(const float2*)(A+4);
            F3 s1 = {a0.x, a0.y, a1.x};
            F3 e1 = {a1.y, a2.x, a2.y};
            F3 r13 = sub(s2, s1), r14 = sub(e2, s1);
            F3 r23 = sub(s2, e1), r24 = sub(e2, e1);
            F3 f0 = crs(r13, r14);
            F3 f1 = crs(r14, r24);
            F3 f2 = crs(r24, r23);
            F3 f3 = crs(r23, r13);
            float ss0 = dt(f0,f0), ss1 = dt(f1,f1), ss2 = dt(f2,f2), ss3 = dt(f3,f3);
            rd01[f][k] = dt(f0,f1); rd12[f][k] = dt(f1,f2);
            rd23[f][k] = dt(f2,f3); rd30[f][k] = dt(f3,f0);
            q01[f][k] = ss0*ss1; q12[f][k] = ss1*ss2;
            q23[f][k] = ss2*ss3; q30[f][k] = ss3*ss0;
            // (r34 x r12) . r13 == -(f3 . r14): reuse f3, skip the 5th cross.
            sg[f][k] = dt(f3, r14);
        }
    }
    // 32 independent rsqrts.
    float i01[2][4], i12[2][4], i23[2][4], i30[2][4];
    #pragma unroll
    for (int f = 0; f < 2; ++f)
    #pragma unroll
    for (int k = 0; k < 4; ++k){
        i01[f][k] = rsqrtf(fmaxf(q01[f][k], 1e-30f));
        i12[f][k] = rsqrtf(fmaxf(q12[f][k], 1e-30f));
        i23[f][k] = rsqrtf(fmaxf(q23[f][k], 1e-30f));
        i30[f][k] = rsqrtf(fmaxf(q30[f][k], 1e-30f));
    }
    // 32 asin groups + combine + store.
    #pragma unroll
    for (int f = 0; f < 2; ++f)
    #pragma unroll
    for (int k = 0; k < 4; ++k){
        float t = asin_fast(clamp1(rd01[f][k] * i01[f][k]))
                + asin_fast(clamp1(rd12[f][k] * i12[f][k]))
                + asin_fast(clamp1(rd23[f][k] * i23[f][k]))
                + asin_fast(clamp1(rd30[f][k] * i30[f][k]));
        // ref: mult = (sign<=0) ? -1 : 1, sign = -sg  =>  negate when sg >= 0.
        float r = (sg[f][k] >= 0.0f ? -t : t) * 0.07957747154594767f;  // 1/(4*pi)
        g[w][f][(k << 6) | lane] = r;   // (q+4k)*16+n == 64k+lane
    }
    __syncthreads();

    // Lanes 0..49: path-pair sums for both frames -> gp[b][pp][f] (coalesced for
    // k_vel). Lanes 50..51: the two overlap flags.
    if (lane < 50){
        int f = lane >= 25 ? 1 : 0;
        int pp = lane - f * 25;
        int i = pp / 5, j = pp - i * 5;
        int poi = (int)((PO_PK >> (i*5)) & 31), pci = (int)((PC_PK >> (i*5)) & 31);
        int poj = (int)((PO_PK >> (j*5)) & 31), pcj = (int)((PC_PK >> (j*5)) & 31);
        float s = 0.0f;
        for (int a = 0; a < pci; ++a)
            for (int b = 0; b < pcj; ++b)
                s += g[w][f][(poi + a) * 16 + (poj + b)];
        int fr = fr0 + f;
        int bb = fr / FF, ff = fr - bb * FF;
        gp[((size_t)bb * 25 + pp) * FF + ff] = s;
    } else if (lane < 52){
        int f = lane - 50;
        const float* e = ext[w][f];
        flags[fr0 + f] = (e[1] >= e[4] && e[5] >= e[0] &&
                          e[3] >= e[6] && e[7] >= e[2]) ? 1 : 0;
    }
}

// Masked frame-diff, max over 25 path-pairs. gp is [b][pp][f]: lane-contiguous in f.
__global__ void __launch_bounds__(256) k_vel(const float* __restrict__ gp,
                                             const int* __restrict__ flags,
                                             float* __restrict__ out){
    int b = blockIdx.x;
    int f = threadIdx.x;
    if (f >= FF - 1) return;
    const int* fl = flags + b * FF;

    int v0 = fl[f] | fl[f + 1];
    if (f > 0) v0 |= fl[f - 1];
    float mk0 = v0 ? 1.0f : 0.0f;

    int v1 = fl[f] | fl[f + 1];
    if (f + 2 < FF) v1 |= fl[f + 2];
    float mk1 = v1 ? 1.0f : 0.0f;

    const float* gb = gp + (size_t)b * 25 * FF + f;
    float mx = 0.0f;
    #pragma unroll
    for (int p = 0; p < 25; ++p){
        float g0 = gb[p * FF];
        float g1 = gb[p * FF + 1];
        float d = fabsf(g1 * mk1 - g0 * mk0);
        mx = fmaxf(mx, d);
    }
    out[b * (FF - 1) + f] = mx;
}

extern "C" void kernel_launch(void* const* d_in, const int* in_sizes, int n_in,
                              void* d_out, int out_size, void* d_ws, size_t ws_size,
                              hipStream_t stream) {
    const float* m1 = (const float*)d_in[0];
    const float* m2 = (const float*)d_in[1];
    float* gp    = (float*)d_ws;                                   // BB*25*FF floats
    int*   flags = (int*)((char*)d_ws + (size_t)BB * 25 * FF * 4); // NFRM ints
    float* out = (float*)d_out;

    k_main<<<NFRM / 8, 256, 0, stream>>>(m1, m2, gp, flags);
    k_vel<<<BB, 256, 0, stream>>>(gp, flags, out);
}

// Round 13
// 75.643 us; speedup vs baseline: 1.0590x; 1.0384x over previous
//
#include <hip/hip_runtime.h>
#include <math.h>

// Problem constants: B=64, F=240, J=22, 16 segments, 5 paths.
#define BB 64
#define FF 240
#define NJ 22
#define NFRM (BB * FF)

// Segment joint tables bit-packed 5 bits/entry into constexpr immediates.
#define PK8(a0,a1,a2,a3,a4,a5,a6,a7) \
  (  (unsigned long long)(a0)        | ((unsigned long long)(a1) << 5)  \
   | ((unsigned long long)(a2) << 10)| ((unsigned long long)(a3) << 15) \
   | ((unsigned long long)(a4) << 20)| ((unsigned long long)(a5) << 25) \
   | ((unsigned long long)(a6) << 30)| ((unsigned long long)(a7) << 35) )
static constexpr unsigned long long SEG_S_LO = PK8(2,5,8,1,4,7,3,6);
static constexpr unsigned long long SEG_S_HI = PK8(9,12,14,17,19,13,16,18);
static constexpr unsigned long long SEG_E_LO = PK8(5,8,11,4,7,10,6,9);
static constexpr unsigned long long SEG_E_HI = PK8(12,15,17,19,21,16,18,20);
// Path offset/count tables, 5 bits/entry.
static constexpr unsigned PO_PK = 0u | (3u<<5) | (6u<<10) | (10u<<15) | (13u<<20);
static constexpr unsigned PC_PK = 3u | (3u<<5) | (4u<<10) | (3u<<15)  | (3u<<20);

__device__ __forceinline__ int seg_start(int m){
    unsigned long long p = (m < 8) ? SEG_S_LO : SEG_S_HI;
    return (int)((p >> ((m & 7) * 5)) & 31);
}
__device__ __forceinline__ int seg_end(int m){
    unsigned long long p = (m < 8) ? SEG_E_LO : SEG_E_HI;
    return (int)((p >> ((m & 7) * 5)) & 31);
}

// Packed fp32: the lane's TWO FRAMES ride VOP3P packed-fp32 (v_pk_fma_f32 etc).
// Register-only — all LDS traffic stays plain float.
typedef float v2 __attribute__((ext_vector_type(2)));
__device__ __forceinline__ v2 vset(float a){ v2 r; r.x = a; r.y = a; return r; }
__device__ __forceinline__ v2 vfma(v2 a, v2 b, v2 c){ return __builtin_elementwise_fma(a, b, c); }

struct V3p { v2 x, y, z; };
__device__ __forceinline__ V3p subp(V3p a, V3p b){ return {a.x-b.x, a.y-b.y, a.z-b.z}; }
__device__ __forceinline__ V3p crsp(V3p a, V3p b){
    return { vfma(a.y, b.z, -(a.z*b.y)), vfma(a.z, b.x, -(a.x*b.z)), vfma(a.x, b.y, -(a.y*b.x)) };
}
__device__ __forceinline__ v2 dtp(V3p a, V3p b){ return vfma(a.x, b.x, vfma(a.y, b.y, a.z*b.z)); }
__device__ __forceinline__ v2 clamp1p(v2 d){
    return __builtin_elementwise_min(__builtin_elementwise_max(d, vset(-1.0f)), vset(1.0f));
}
// Branchless asin, Abramowitz-Stegun 4.4.45 (3-term), |err| <= 6.8e-5 abs.
// Raw v_sqrt_f32 (arg in [0,2]) — proven in R8-R11 passing runs.
__device__ __forceinline__ v2 asin_fast2(v2 d){
    v2 ax = __builtin_elementwise_abs(d);
    v2 p = vfma(vfma(vfma(vset(-0.0187293f), ax, vset(0.0742610f)), ax, vset(-0.2121144f)),
                ax, vset(1.5707288f));
    v2 om = vset(1.0f) - ax;
    v2 s; s.x = __builtin_amdgcn_sqrtf(om.x); s.y = __builtin_amdgcn_sqrtf(om.y);
    v2 r = vset(1.57079632679f) - s * p;
    return __builtin_elementwise_copysign(r, d);
}

// 256-thread block = 4 waves; each wave owns TWO frames (packed .x/.y).
// R9-proven scaffolding: float2-staged pts LDS, plain-float LDS reads (lane
// gathers its segment endpoints directly; the two frames' reads are 264 B
// apart -> ds_read2_b32 pairs), R9 reduction/flag tail. The only new element
// vs R9 is the register-level packed arithmetic.
__global__ void __launch_bounds__(256) k_main(const float* __restrict__ m1,
                                              const float* __restrict__ m2,
                                              float* __restrict__ gp,
                                              int* __restrict__ flags){
    __shared__ __align__(8) float pts[4][2][136]; // [wave][motion][frame*66+idx], 132 used
    __shared__ float g[4][2][256];                // [wave][frame][m*16+n]
    __shared__ float ext[4][2][8];                // [wave][frame][{nx,xx,nz,xz} x 2 mot]
    int tid = threadIdx.x;
    int w = tid >> 6, lane = tid & 63;
    int fr0 = blockIdx.x * 8 + w * 2;   // this wave's frames: fr0, fr0+1

    // Stage 2 frames x 66 floats per motion = 66 float2 per motion (contiguous).
    const float2* gs1 = (const float2*)(m1 + (size_t)fr0 * 66);
    const float2* gs2 = (const float2*)(m2 + (size_t)fr0 * 66);
    for (int u = lane; u < 132; u += 64){
        bool a = u < 66;
        int v = a ? u : u - 66;
        ((float2*)pts[w][a ? 0 : 1])[v] = (a ? gs1 : gs2)[v];
    }
    __syncthreads();

    // Bbox extrema (lanes 0..15): 2 frames x 2 motions x {x,z} x {min,max}.
    if (lane < 16){
        int f = lane >> 3;
        int sel = lane & 7;          // mot = sel>>2; 0=nx 1=xx 2=nz 3=xz
        int mot = sel >> 2;
        int c = sel & 2;             // 0 -> x, 2 -> z
        bool mx = sel & 1;           // max via -min(-v)
        const float* P = &pts[w][mot][f * 66];
        float a = 1e30f;
        #pragma unroll
        for (int j = 0; j < NJ; ++j){
            float v = P[j*3 + c];
            a = fminf(a, mx ? -v : v);
        }
        ext[w][f][sel] = mx ? -a : a;
    }

    // GLI: gather endpoints for both frames from pts (plain float reads, frame
    // pair 66 floats apart), pack into v2, run 4 packed pair-chains per lane.
    int n = lane & 15, q = lane >> 4;
    const float* P1 = pts[w][0];
    const float* P2 = pts[w][1];
    int js2 = seg_start(n) * 3, je2 = seg_end(n) * 3;
    V3p s2 = { v2{P2[js2  ], P2[66+js2  ]},
               v2{P2[js2+1], P2[66+js2+1]},
               v2{P2[js2+2], P2[66+js2+2]} };
    V3p e2 = { v2{P2[je2  ], P2[66+je2  ]},
               v2{P2[je2+1], P2[66+je2+1]},
               v2{P2[je2+2], P2[66+je2+2]} };

    v2 rd01[4], rd12[4], rd23[4], rd30[4];
    v2 q01[4], q12[4], q23[4], q30[4];
    v2 sg[4];
    #pragma unroll
    for (int k = 0; k < 4; ++k){
        int m = q + 4 * k;
        int js1 = seg_start(m) * 3, je1 = seg_end(m) * 3;
        V3p s1 = { v2{P1[js1  ], P1[66+js1  ]},
                   v2{P1[js1+1], P1[66+js1+1]},
                   v2{P1[js1+2], P1[66+js1+2]} };
        V3p e1 = { v2{P1[je1  ], P1[66+je1  ]},
                   v2{P1[je1+1], P1[66+je1+1]},
                   v2{P1[je1+2], P1[66+je1+2]} };
        V3p r13 = subp(s2, s1), r14 = subp(e2, s1);
        V3p r23 = subp(s2, e1), r24 = subp(e2, e1);
        V3p f0 = crsp(r13, r14);
        V3p f1 = crsp(r14, r24);
        V3p f2 = crsp(r24, r23);
        V3p f3 = crsp(r23, r13);
        v2 ss0 = dtp(f0,f0), ss1 = dtp(f1,f1), ss2 = dtp(f2,f2), ss3 = dtp(f3,f3);
        rd01[k] = dtp(f0,f1); rd12[k] = dtp(f1,f2);
        rd23[k] = dtp(f2,f3); rd30[k] = dtp(f3,f0);
        q01[k] = ss0*ss1; q12[k] = ss1*ss2; q23[k] = ss2*ss3; q30[k] = ss3*ss0;
        // (r34 x r12) . r13 == -(f3 . r14): reuse f3, skip the 5th cross.
        sg[k] = dtp(f3, r14);
    }
    // 32 independent rsqrts (libm, proven in R9).
    v2 i01[4], i12[4], i23[4], i30[4];
    #pragma unroll
    for (int k = 0; k < 4; ++k){
        i01[k].x = rsqrtf(fmaxf(q01[k].x, 1e-30f));
        i01[k].y = rsqrtf(fmaxf(q01[k].y, 1e-30f));
        i12[k].x = rsqrtf(fmaxf(q12[k].x, 1e-30f));
        i12[k].y = rsqrtf(fmaxf(q12[k].y, 1e-30f));
        i23[k].x = rsqrtf(fmaxf(q23[k].x, 1e-30f));
        i23[k].y = rsqrtf(fmaxf(q23[k].y, 1e-30f));
        i30[k].x = rsqrtf(fmaxf(q30[k].x, 1e-30f));
        i30[k].y = rsqrtf(fmaxf(q30[k].y, 1e-30f));
    }
    // Packed asins + combine + store.
    #pragma unroll
    for (int k = 0; k < 4; ++k){
        v2 t = asin_fast2(clamp1p(rd01[k] * i01[k]))
             + asin_fast2(clamp1p(rd12[k] * i12[k]))
             + asin_fast2(clamp1p(rd23[k] * i23[k]))
             + asin_fast2(clamp1p(rd30[k] * i30[k]));
        // ref: mult = (sign<=0) ? -1 : 1, sign = -sg  =>  negate when sg >= 0.
        float r0 = (sg[k].x >= 0.0f ? -t.x : t.x) * 0.07957747154594767f;  // 1/(4*pi)
        float r1 = (sg[k].y >= 0.0f ? -t.y : t.y) * 0.07957747154594767f;
        g[w][0][(k << 6) | lane] = r0;   // (q+4k)*16+n == 64k+lane
        g[w][1][(k << 6) | lane] = r1;
    }
    __syncthreads();

    // Lanes 0..49: path-pair sums for both frames -> gp[b][pp][f] (coalesced for
    // k_vel). Lanes 50..51: the two overlap flags. (R9-proven tail.)
    if (lane < 50){
        int f = lane >= 25 ? 1 : 0;
        int pp = lane - f * 25;
        int i = pp / 5, j = pp - i * 5;
        int poi = (int)((PO_PK >> (i*5)) & 31), pci = (int)((PC_PK >> (i*5)) & 31);
        int poj = (int)((PO_PK >> (j*5)) & 31), pcj = (int)((PC_PK >> (j*5)) & 31);
        float s = 0.0f;
        for (int a = 0; a < pci; ++a)
            for (int b = 0; b < pcj; ++b)
                s += g[w][f][(poi + a) * 16 + (poj + b)];
        int fr = fr0 + f;
        int bb = fr / FF, ff = fr - bb * FF;
        gp[((size_t)bb * 25 + pp) * FF + ff] = s;
    } else if (lane < 52){
        int f = lane - 50;
        const float* e = ext[w][f];
        flags[fr0 + f] = (e[1] >= e[4] && e[5] >= e[0] &&
                          e[3] >= e[6] && e[7] >= e[2]) ? 1 : 0;
    }
}

// Masked frame-diff, max over 25 path-pairs. gp is [b][pp][f]: lane-contiguous in f.
__global__ void __launch_bounds__(256) k_vel(const float* __restrict__ gp,
                                             const int* __restrict__ flags,
                                             float* __restrict__ out){
    int b = blockIdx.x;
    int f = threadIdx.x;
    if (f >= FF - 1) return;
    const int* fl = flags + b * FF;

    int v0 = fl[f] | fl[f + 1];
    if (f > 0) v0 |= fl[f - 1];
    float mk0 = v0 ? 1.0f : 0.0f;

    int v1 = fl[f] | fl[f + 1];
    if (f + 2 < FF) v1 |= fl[f + 2];
    float mk1 = v1 ? 1.0f : 0.0f;

    const float* gb = gp + (size_t)b * 25 * FF + f;
    float mx = 0.0f;
    #pragma unroll
    for (int p = 0; p < 25; ++p){
        float g0 = gb[p * FF];
        float g1 = gb[p * FF + 1];
        float d = fabsf(g1 * mk1 - g0 * mk0);
        mx = fmaxf(mx, d);
    }
    out[b * (FF - 1) + f] = mx;
}

extern "C" void kernel_launch(void* const* d_in, const int* in_sizes, int n_in,
                              void* d_out, int out_size, void* d_ws, size_t ws_size,
                              hipStream_t stream) {
    const float* m1 = (const float*)d_in[0];
    const float* m2 = (const float*)d_in[1];
    float* gp    = (float*)d_ws;                                   // BB*25*FF floats
    int*   flags = (int*)((char*)d_ws + (size_t)BB * 25 * FF * 4); // NFRM ints
    float* out = (float*)d_out;

    k_main<<<NFRM / 8, 256, 0, stream>>>(m1, m2, gp, flags);
    k_vel<<<BB, 256, 0, stream>>>(gp, flags, out);
}